// Round 5
// baseline (1053.019 us; speedup 1.0000x reference)
//
#include <hip/hip_runtime.h>
#include <hip/hip_bf16.h>
#include <hip/hip_cooperative_groups.h>

namespace cg = cooperative_groups;

constexpr int N_NODES = 100000;
constexpr int N_EDGES = 600000;
constexpr int D = 128;          // feature dim; OUT_DIM is also 128

constexpr int SCAN_CHUNK = 1024;
constexpr int N_SCAN_BLOCKS = (N_NODES + SCAN_CHUNK - 1) / SCAN_CHUNK; // 98
constexpr int COOP_BLOCKS = 1024;   // 4 blocks/CU on 256 CUs — co-resident with margin

// ---------------- workspace layout (bytes) ----------------
// counts aliases the head of the edges buffer (disjoint lifetimes:
// counts dead after the chunk-scan phase; edges first written in reorder phase).
constexpr size_t X16_OFF    = 0;          // x bf16: 100000*128*2 = 25,600,000
constexpr size_t WP_OFF     = 25600000;   // packed W bf16: 65,536
constexpr size_t RS_OFF     = 25665536;   // row_start: 100001 ints
constexpr size_t CUR_OFF    = 26065664;   // cursor: 100000 ints
constexpr size_t BS_OFF     = 26465664;   // block_sums: 128 ints
constexpr size_t EDGES_OFF  = 26466176;   // int2 x 600000 = 4.8 MB (end ~31.3 MB)
constexpr size_t COUNTS_OFF = EDGES_OFF;  // aliased

typedef __attribute__((ext_vector_type(8))) short short8;
typedef __attribute__((ext_vector_type(4))) float float4v;

__device__ inline unsigned short f2bf(float f) {
    union { float f; unsigned int u; } v; v.f = f;
    unsigned int u = v.u + 0x7fffu + ((v.u >> 16) & 1u);  // RNE
    return (unsigned short)(u >> 16);
}
__device__ inline float bf2f(unsigned int lo16) {
    union { unsigned int u; float f; } v; v.u = lo16 << 16;
    return v.f;
}

// ---------------------------------------------------------------------------
// ONE cooperative kernel for the whole pre-GEMM pipeline:
//   P0 zero counts | P1 histogram + cast x->bf16 + pack W | P2 chunk scan
//   P3 top scan | P4 add offsets / init cursor | P5 reorder edges
// grid.sync() between phases; __threadfence() (agent scope => cross-XCD
// coherent on gfx950) brackets non-atomic cross-block data flows.
// NOTE: no early returns anywhere — every thread reaches every grid.sync().
// ---------------------------------------------------------------------------
__global__ __launch_bounds__(256) void build_kernel(
    const float* __restrict__ x, uint4* __restrict__ x16,
    const float* __restrict__ W, unsigned short* __restrict__ Wp,
    const int* __restrict__ rows, const int* __restrict__ cols,
    const float* __restrict__ vals,
    int* __restrict__ counts, int* __restrict__ row_start,
    int* __restrict__ cursor, int* __restrict__ block_sums,
    int2* __restrict__ edges)
{
    cg::grid_group grid = cg::this_grid();
    const int tid = blockIdx.x * 256 + threadIdx.x;
    const int T   = COOP_BLOCKS * 256;

    // ---- P0: zero the histogram ----
    for (int i = tid; i < N_NODES; i += T) counts[i] = 0;
    __threadfence();
    grid.sync();

    // ---- P1: histogram (atomics) + cast x + pack W (independent) ----
    for (int e = tid; e < N_EDGES; e += T) atomicAdd(&counts[rows[e]], 1);
    for (int g = tid; g < N_NODES * D / 8; g += T) {
        const float4* xp = reinterpret_cast<const float4*>(x + (size_t)g * 8);
        float4 a = xp[0], c = xp[1];
        uint4 o;
        o.x = (unsigned int)f2bf(a.x) | ((unsigned int)f2bf(a.y) << 16);
        o.y = (unsigned int)f2bf(a.z) | ((unsigned int)f2bf(a.w) << 16);
        o.z = (unsigned int)f2bf(c.x) | ((unsigned int)f2bf(c.y) << 16);
        o.w = (unsigned int)f2bf(c.z) | ((unsigned int)f2bf(c.w) << 16);
        x16[g] = o;
    }
    // Wp B-fragment order for mfma_f32_16x16x32_bf16:
    //   b_frag[lane][j] = W[s*32 + (lane>>4)*8 + j][jt*16 + (lane&15)]
    //   at linear index ((s*8 + jt)*64 + lane)*8 + j.
    for (int idx = tid; idx < 8 * 8 * 64 * 8; idx += T) {
        int j    = idx & 7;
        int lane = (idx >> 3) & 63;
        int jt   = (idx >> 9) & 7;
        int s    = idx >> 12;
        int k = s * 32 + (lane >> 4) * 8 + j;
        int n = jt * 16 + (lane & 15);
        Wp[idx] = f2bf(W[k * 128 + n]);
    }
    __threadfence();
    grid.sync();

    // ---- P2: per-chunk exclusive scan (blocks 0..97, 1024 counts each) ----
    __shared__ int sdata[256];
    if (blockIdx.x < N_SCAN_BLOCKS) {
        const int b = blockIdx.x, t = threadIdx.x;
        const int base = b * SCAN_CHUNK + t * 4;
        int v[4];
        #pragma unroll
        for (int i = 0; i < 4; i++) {
            int idx = base + i;
            v[i] = (idx < N_NODES) ? counts[idx] : 0;
        }
        int tsum = v[0] + v[1] + v[2] + v[3];
        sdata[t] = tsum;
        __syncthreads();
        for (int off = 1; off < 256; off <<= 1) {
            int val = (t >= off) ? sdata[t - off] : 0;
            __syncthreads();
            sdata[t] += val;
            __syncthreads();
        }
        if (t == 255) block_sums[b] = sdata[255];
        int run = sdata[t] - tsum;
        #pragma unroll
        for (int i = 0; i < 4; i++) {
            int idx = base + i;
            if (idx < N_NODES) row_start[idx] = run;
            run += v[i];
        }
    }
    __threadfence();
    grid.sync();

    // ---- P3: scan the 98 block sums (block 0; all 256 threads iterate) ----
    if (blockIdx.x == 0) {
        const int t = threadIdx.x;
        int v = 0;
        if (t < 128) {
            v = (t < N_SCAN_BLOCKS) ? block_sums[t] : 0;
            sdata[t] = v;
        }
        __syncthreads();
        for (int off = 1; off < 128; off <<= 1) {
            int val = (t >= off && t < 128) ? sdata[t - off] : 0;
            __syncthreads();
            if (t < 128) sdata[t] += val;
            __syncthreads();
        }
        if (t < N_SCAN_BLOCKS) block_sums[t] = sdata[t] - v;  // exclusive
    }
    __threadfence();
    grid.sync();

    // ---- P4: add chunk offsets; init cursor; terminate row_start ----
    for (int i = tid; i < N_NODES; i += T) {
        int v = row_start[i] + block_sums[i >> 10];
        row_start[i] = v;
        cursor[i]    = v;
    }
    if (tid == 0) row_start[N_NODES] = N_EDGES;
    __threadfence();
    grid.sync();

    // ---- P5: reorder edges into row-sorted (col, val) pairs ----
    for (int e = tid; e < N_EDGES; e += T) {
        int pos = atomicAdd(&cursor[rows[e]], 1);
        edges[pos] = make_int2(cols[e], __float_as_int(vals[e]));
    }
}

// ---------------------------------------------------------------------------
// Fused aggregate + GEMM + relu.
// Block = 4 waves = 64 rows; wave w owns rows row0 = blk*64 + w*16 .. +15.
//
// Phase A: wave splits into 4 groups of 16 lanes; group g, t-slot processes
// node m_local = t*4 + g. Lane gl of a group gathers uint4 = features
// [gl*8..gl*8+7] of x16[col], accumulates fp32 (4-wide edge unroll for MLP),
// packs bf16, writes one 16B A-frag piece to LDS at frag index
// s*64 + m*4 + q (s=gl>>2, q=gl&3) — conflict-free b128 writes and reads.
//
// Phase B: mfma_f32_16x16x32_bf16; A s=0..3 from LDS (= h rows), s=4..7
// straight from global x16; B from pre-packed Wp (lane-contiguous 16B, L2).
// C/D layout: col = lane&15, row = (lane>>4)*4 + reg  [m89-verified, R3-passed].
// ---------------------------------------------------------------------------
__global__ __launch_bounds__(256) void fused_agg_gemm_kernel(
    const uint4* __restrict__ x16v,
    const unsigned short* __restrict__ x16s,
    const int* __restrict__ row_start,
    const int2* __restrict__ edges,
    const unsigned short* __restrict__ Wp,
    float* __restrict__ out)
{
    __shared__ uint4 lds4[4 * 256];   // wave*256 + s*64 + m*4 + q  (16 KB)

    const int tid  = threadIdx.x;
    const int wave = tid >> 6;
    const int lane = tid & 63;
    const int row0 = blockIdx.x * 64 + wave * 16;

    // ---------------- Phase A: aggregate 16 rows into LDS ----------------
    {
        const int g   = lane >> 4;      // group 0..3
        const int gl  = lane & 15;      // lane in group
        const int s_w = gl >> 2;
        const int q_w = gl & 3;
        for (int t = 0; t < 4; t++) {
            const int m_local = t * 4 + g;
            const int n = row0 + m_local;
            float a0=0.f,a1=0.f,a2=0.f,a3=0.f,a4=0.f,a5=0.f,a6=0.f,a7=0.f;
            if (n < N_NODES) {
                int i = row_start[n];
                const int e_end = row_start[n + 1];
                for (; i + 3 < e_end; i += 4) {
                    int2 e0 = edges[i];
                    int2 e1 = edges[i + 1];
                    int2 e2 = edges[i + 2];
                    int2 e3 = edges[i + 3];
                    uint4 p0 = x16v[(size_t)e0.x * 16 + gl];
                    uint4 p1 = x16v[(size_t)e1.x * 16 + gl];
                    uint4 p2 = x16v[(size_t)e2.x * 16 + gl];
                    uint4 p3 = x16v[(size_t)e3.x * 16 + gl];
                    float v0 = __int_as_float(e0.y);
                    float v1 = __int_as_float(e1.y);
                    float v2 = __int_as_float(e2.y);
                    float v3 = __int_as_float(e3.y);
                    a0 += v0 * bf2f(p0.x & 0xffffu) + v1 * bf2f(p1.x & 0xffffu)
                        + v2 * bf2f(p2.x & 0xffffu) + v3 * bf2f(p3.x & 0xffffu);
                    a1 += v0 * bf2f(p0.x >> 16)     + v1 * bf2f(p1.x >> 16)
                        + v2 * bf2f(p2.x >> 16)     + v3 * bf2f(p3.x >> 16);
                    a2 += v0 * bf2f(p0.y & 0xffffu) + v1 * bf2f(p1.y & 0xffffu)
                        + v2 * bf2f(p2.y & 0xffffu) + v3 * bf2f(p3.y & 0xffffu);
                    a3 += v0 * bf2f(p0.y >> 16)     + v1 * bf2f(p1.y >> 16)
                        + v2 * bf2f(p2.y >> 16)     + v3 * bf2f(p3.y >> 16);
                    a4 += v0 * bf2f(p0.z & 0xffffu) + v1 * bf2f(p1.z & 0xffffu)
                        + v2 * bf2f(p2.z & 0xffffu) + v3 * bf2f(p3.z & 0xffffu);
                    a5 += v0 * bf2f(p0.z >> 16)     + v1 * bf2f(p1.z >> 16)
                        + v2 * bf2f(p2.z >> 16)     + v3 * bf2f(p3.z >> 16);
                    a6 += v0 * bf2f(p0.w & 0xffffu) + v1 * bf2f(p1.w & 0xffffu)
                        + v2 * bf2f(p2.w & 0xffffu) + v3 * bf2f(p3.w & 0xffffu);
                    a7 += v0 * bf2f(p0.w >> 16)     + v1 * bf2f(p1.w >> 16)
                        + v2 * bf2f(p2.w >> 16)     + v3 * bf2f(p3.w >> 16);
                }
                for (; i < e_end; i++) {
                    int2 e0 = edges[i];
                    float v0 = __int_as_float(e0.y);
                    uint4 p0 = x16v[(size_t)e0.x * 16 + gl];
                    a0 += v0 * bf2f(p0.x & 0xffffu);
                    a1 += v0 * bf2f(p0.x >> 16);
                    a2 += v0 * bf2f(p0.y & 0xffffu);
                    a3 += v0 * bf2f(p0.y >> 16);
                    a4 += v0 * bf2f(p0.z & 0xffffu);
                    a5 += v0 * bf2f(p0.z >> 16);
                    a6 += v0 * bf2f(p0.w & 0xffffu);
                    a7 += v0 * bf2f(p0.w >> 16);
                }
            }
            uint4 o;
            o.x = (unsigned int)f2bf(a0) | ((unsigned int)f2bf(a1) << 16);
            o.y = (unsigned int)f2bf(a2) | ((unsigned int)f2bf(a3) << 16);
            o.z = (unsigned int)f2bf(a4) | ((unsigned int)f2bf(a5) << 16);
            o.w = (unsigned int)f2bf(a6) | ((unsigned int)f2bf(a7) << 16);
            lds4[wave * 256 + s_w * 64 + m_local * 4 + q_w] = o;
        }
    }
    __syncthreads();

    // ---------------- Phase B: MFMA GEMM + relu ----------------
    const int m    = lane & 15;
    const int quad = lane >> 4;

    int arow = row0 + m;
    if (arow >= N_NODES) arow = N_NODES - 1;   // clamped dup load; stores guarded
    const unsigned short* xrow = x16s + (size_t)arow * D + quad * 8;

    float4v acc[8];
    #pragma unroll
    for (int jt = 0; jt < 8; jt++) acc[jt] = (float4v){0.f, 0.f, 0.f, 0.f};

    #pragma unroll
    for (int s = 0; s < 8; s++) {
        short8 a;
        if (s < 4)
            a = *reinterpret_cast<const short8*>(&lds4[wave * 256 + s * 64 + m * 4 + quad]);
        else
            a = *reinterpret_cast<const short8*>(xrow + (s - 4) * 32);
        #pragma unroll
        for (int jt = 0; jt < 8; jt++) {
            short8 b = *reinterpret_cast<const short8*>(
                Wp + ((size_t)((s * 8 + jt) * 64 + lane)) * 8);
            acc[jt] = __builtin_amdgcn_mfma_f32_16x16x32_bf16(a, b, acc[jt], 0, 0, 0);
        }
    }

    #pragma unroll
    for (int reg = 0; reg < 4; reg++) {
        int r = row0 + quad * 4 + reg;
        if (r < N_NODES) {
            float* orow = out + (size_t)r * D;
            #pragma unroll
            for (int jt = 0; jt < 8; jt++)
                orow[jt * 16 + m] = fmaxf(acc[jt][reg], 0.f);
        }
    }
}

// ---------------------------------------------------------------------------
extern "C" void kernel_launch(void* const* d_in, const int* in_sizes, int n_in,
                              void* d_out, int out_size, void* d_ws, size_t ws_size,
                              hipStream_t stream)
{
    const float* x    = (const float*)d_in[0];
    const int*   rows = (const int*)  d_in[1];
    const int*   cols = (const int*)  d_in[2];
    const float* vals = (const float*)d_in[3];
    const float* W    = (const float*)d_in[4];
    float* out = (float*)d_out;

    char* ws = (char*)d_ws;
    uint4*          x16v  = (uint4*)         (ws + X16_OFF);
    unsigned short* x16s  = (unsigned short*)(ws + X16_OFF);
    unsigned short* Wp    = (unsigned short*)(ws + WP_OFF);
    int*   row_start  = (int*)  (ws + RS_OFF);
    int*   cursor     = (int*)  (ws + CUR_OFF);
    int*   block_sums = (int*)  (ws + BS_OFF);
    int2*  edges      = (int2*) (ws + EDGES_OFF);
    int*   counts     = (int*)  (ws + COUNTS_OFF);   // aliases edges head

    void* args[] = {
        (void*)&x, (void*)&x16v, (void*)&W, (void*)&Wp,
        (void*)&rows, (void*)&cols, (void*)&vals,
        (void*)&counts, (void*)&row_start, (void*)&cursor,
        (void*)&block_sums, (void*)&edges
    };
    hipLaunchCooperativeKernel((const void*)build_kernel,
                               dim3(COOP_BLOCKS), dim3(256), args, 0, stream);

    fused_agg_gemm_kernel<<<(N_NODES + 63) / 64, 256, 0, stream>>>(
        x16v, x16s, row_start, edges, Wp, out);
}

// Round 7
// 206.556 us; speedup vs baseline: 5.0980x; 5.0980x over previous
//
#include <hip/hip_runtime.h>
#include <hip/hip_bf16.h>

constexpr int N_NODES = 100000;
constexpr int N_EDGES = 600000;
constexpr int D = 128;          // feature dim; OUT_DIM is also 128

// ---------------- workspace layout (bytes) ----------------
constexpr size_t X16_OFF  = 0;          // x bf16: 100000*128*2 = 25,600,000
constexpr size_t WP_OFF   = 25600000;   // packed W bf16: 65,536
constexpr size_t HEAD_OFF = 25665536;   // head: 100000 ints (pad to 400,128)
constexpr size_t TB_OFF   = 26065664;   // table: int4 x 600000 = 9.6 MB (end ~35.7 MB)

typedef __attribute__((ext_vector_type(8))) short short8;
typedef __attribute__((ext_vector_type(4))) float float4v;

__device__ inline unsigned short f2bf(float f) {
    union { float f; unsigned int u; } v; v.f = f;
    unsigned int u = v.u + 0x7fffu + ((v.u >> 16) & 1u);  // RNE
    return (unsigned short)(u >> 16);
}
__device__ inline float bf2f(unsigned int lo16) {
    union { unsigned int u; float f; } v; v.u = lo16 << 16;
    return v.f;
}

// ---------------------------------------------------------------------------
// Prep (one dispatch, grid-stride): head = -1 | cast x fp32->bf16 | pack W.
// Wp B-fragment order for mfma_f32_16x16x32_bf16:
//   b_frag[lane][j] = W[s*32 + (lane>>4)*8 + j][jt*16 + (lane&15)]
//   at linear index ((s*8 + jt)*64 + lane)*8 + j.
// ---------------------------------------------------------------------------
__global__ __launch_bounds__(256) void prep_kernel(
    const float* __restrict__ x, uint4* __restrict__ x16,
    const float* __restrict__ W, unsigned short* __restrict__ Wp,
    int* __restrict__ head)
{
    const int tid = blockIdx.x * 256 + threadIdx.x;
    const int T   = gridDim.x * 256;

    for (int i = tid; i < N_NODES; i += T) head[i] = -1;

    for (int idx = tid; idx < 8 * 8 * 64 * 8; idx += T) {
        int j    = idx & 7;
        int lane = (idx >> 3) & 63;
        int jt   = (idx >> 9) & 7;
        int s    = idx >> 12;
        int k = s * 32 + (lane >> 4) * 8 + j;
        int n = jt * 16 + (lane & 15);
        Wp[idx] = f2bf(W[k * 128 + n]);
    }

    for (int g = tid; g < N_NODES * D / 8; g += T) {
        const float4* xp = reinterpret_cast<const float4*>(x + (size_t)g * 8);
        float4 a = xp[0], c = xp[1];
        uint4 o;
        o.x = (unsigned int)f2bf(a.x) | ((unsigned int)f2bf(a.y) << 16);
        o.y = (unsigned int)f2bf(a.z) | ((unsigned int)f2bf(a.w) << 16);
        o.z = (unsigned int)f2bf(c.x) | ((unsigned int)f2bf(c.y) << 16);
        o.w = (unsigned int)f2bf(c.z) | ((unsigned int)f2bf(c.w) << 16);
        x16[g] = o;
    }
}

// ---------------------------------------------------------------------------
// Linked-list binning: one pass, no histogram/scan/reorder.
// table[e] = (col, val_bits, next, 0); head[row] -> most recent edge.
// Chain order is nondeterministic (atomicExch race) — harmless: fp32 sum
// reassociation only, within bf16 tolerance.
// ---------------------------------------------------------------------------
__global__ __launch_bounds__(256) void link_kernel(
    const int* __restrict__ rows, const int* __restrict__ cols,
    const float* __restrict__ vals,
    int* __restrict__ head, int4* __restrict__ table)
{
    int e = blockIdx.x * 256 + threadIdx.x;
    if (e >= N_EDGES) return;
    int old = atomicExch(&head[rows[e]], e);
    table[e] = make_int4(cols[e], __float_as_int(vals[e]), old, 0);
}

// ---------------------------------------------------------------------------
// Fused aggregate + GEMM + relu.
// Block = 4 waves = 64 rows; wave w owns rows row0 = blk*64 + w*16 .. +15.
//
// Phase A: wave splits into 4 groups of 16 lanes; group g walks the chains
// of its 4 rows (m_local = t*4+g, t=0..3) INTERLEAVED: per loop iteration up
// to 4 independent table loads + 4 independent x-gathers are in flight; the
// serial dependency is only table[cur] -> cur = next. Lane gl holds features
// [gl*8..gl*8+7]; fp32 accumulate; pack bf16; one 16B A-frag piece to LDS at
// frag index s*64 + m*4 + q (s=gl>>2, q=gl&3) — conflict-free b128 traffic.
// NOTE (R5 bug): loop condition must be "any cur[t] >= 0"; the old
// (cur0|cur1|cur2|cur3) != -1 clause is identically false once ANY chain
// ends (-1 is absorbing under OR) — it truncated the other chains.
//
// Phase B: mfma_f32_16x16x32_bf16; A s=0..3 from LDS (= h rows), s=4..7
// straight from global x16; B from pre-packed Wp (lane-contiguous 16B, L2).
// C/D layout: col = lane&15, row = (lane>>4)*4 + reg  [m89-verified, R3-passed].
// ---------------------------------------------------------------------------
__global__ __launch_bounds__(256) void fused_agg_gemm_kernel(
    const uint4* __restrict__ x16v,
    const unsigned short* __restrict__ x16s,
    const int* __restrict__ head,
    const int4* __restrict__ table,
    const unsigned short* __restrict__ Wp,
    float* __restrict__ out)
{
    __shared__ uint4 lds4[4 * 256];   // wave*256 + s*64 + m*4 + q  (16 KB)

    const int tid  = threadIdx.x;
    const int wave = tid >> 6;
    const int lane = tid & 63;
    const int row0 = blockIdx.x * 64 + wave * 16;

    // ---------------- Phase A: aggregate 16 rows into LDS ----------------
    {
        const int g   = lane >> 4;      // group 0..3
        const int gl  = lane & 15;      // lane in group
        const int s_w = gl >> 2;
        const int q_w = gl & 3;

        int cur[4];
        float acc[4][8];
        #pragma unroll
        for (int t = 0; t < 4; t++) {
            int n = row0 + t * 4 + g;
            cur[t] = (n < N_NODES) ? head[n] : -1;
            #pragma unroll
            for (int j = 0; j < 8; j++) acc[t][j] = 0.f;
        }

        while (cur[0] >= 0 || cur[1] >= 0 || cur[2] >= 0 || cur[3] >= 0) {
            int4 tb[4];
            #pragma unroll
            for (int t = 0; t < 4; t++)
                if (cur[t] >= 0) tb[t] = table[cur[t]];
            uint4 p[4];
            #pragma unroll
            for (int t = 0; t < 4; t++)
                if (cur[t] >= 0) p[t] = x16v[(size_t)tb[t].x * 16 + gl];
            #pragma unroll
            for (int t = 0; t < 4; t++) {
                if (cur[t] >= 0) {
                    float v = __int_as_float(tb[t].y);
                    acc[t][0] += v * bf2f(p[t].x & 0xffffu);
                    acc[t][1] += v * bf2f(p[t].x >> 16);
                    acc[t][2] += v * bf2f(p[t].y & 0xffffu);
                    acc[t][3] += v * bf2f(p[t].y >> 16);
                    acc[t][4] += v * bf2f(p[t].z & 0xffffu);
                    acc[t][5] += v * bf2f(p[t].z >> 16);
                    acc[t][6] += v * bf2f(p[t].w & 0xffffu);
                    acc[t][7] += v * bf2f(p[t].w >> 16);
                    cur[t] = tb[t].z;
                }
            }
        }

        #pragma unroll
        for (int t = 0; t < 4; t++) {
            const int m_local = t * 4 + g;
            uint4 o;
            o.x = (unsigned int)f2bf(acc[t][0]) | ((unsigned int)f2bf(acc[t][1]) << 16);
            o.y = (unsigned int)f2bf(acc[t][2]) | ((unsigned int)f2bf(acc[t][3]) << 16);
            o.z = (unsigned int)f2bf(acc[t][4]) | ((unsigned int)f2bf(acc[t][5]) << 16);
            o.w = (unsigned int)f2bf(acc[t][6]) | ((unsigned int)f2bf(acc[t][7]) << 16);
            lds4[wave * 256 + s_w * 64 + m_local * 4 + q_w] = o;
        }
    }
    __syncthreads();

    // ---------------- Phase B: MFMA GEMM + relu ----------------
    const int m    = lane & 15;
    const int quad = lane >> 4;

    int arow = row0 + m;
    if (arow >= N_NODES) arow = N_NODES - 1;   // clamped dup load; stores guarded
    const unsigned short* xrow = x16s + (size_t)arow * D + quad * 8;

    float4v acc[8];
    #pragma unroll
    for (int jt = 0; jt < 8; jt++) acc[jt] = (float4v){0.f, 0.f, 0.f, 0.f};

    #pragma unroll
    for (int s = 0; s < 8; s++) {
        short8 a;
        if (s < 4)
            a = *reinterpret_cast<const short8*>(&lds4[wave * 256 + s * 64 + m * 4 + quad]);
        else
            a = *reinterpret_cast<const short8*>(xrow + (s - 4) * 32);
        #pragma unroll
        for (int jt = 0; jt < 8; jt++) {
            short8 b = *reinterpret_cast<const short8*>(
                Wp + ((size_t)((s * 8 + jt) * 64 + lane)) * 8);
            acc[jt] = __builtin_amdgcn_mfma_f32_16x16x32_bf16(a, b, acc[jt], 0, 0, 0);
        }
    }

    #pragma unroll
    for (int reg = 0; reg < 4; reg++) {
        int r = row0 + quad * 4 + reg;
        if (r < N_NODES) {
            float* orow = out + (size_t)r * D;
            #pragma unroll
            for (int jt = 0; jt < 8; jt++)
                orow[jt * 16 + m] = fmaxf(acc[jt][reg], 0.f);
        }
    }
}

// ---------------------------------------------------------------------------
extern "C" void kernel_launch(void* const* d_in, const int* in_sizes, int n_in,
                              void* d_out, int out_size, void* d_ws, size_t ws_size,
                              hipStream_t stream)
{
    const float* x    = (const float*)d_in[0];
    const int*   rows = (const int*)  d_in[1];
    const int*   cols = (const int*)  d_in[2];
    const float* vals = (const float*)d_in[3];
    const float* W    = (const float*)d_in[4];
    float* out = (float*)d_out;

    char* ws = (char*)d_ws;
    uint4*          x16v  = (uint4*)         (ws + X16_OFF);
    unsigned short* x16s  = (unsigned short*)(ws + X16_OFF);
    unsigned short* Wp    = (unsigned short*)(ws + WP_OFF);
    int*            head  = (int*)           (ws + HEAD_OFF);
    int4*           table = (int4*)          (ws + TB_OFF);

    prep_kernel<<<2048, 256, 0, stream>>>(x, x16v, W, Wp, head);
    link_kernel<<<(N_EDGES + 255) / 256, 256, 0, stream>>>(rows, cols, vals, head, table);
    fused_agg_gemm_kernel<<<(N_NODES + 63) / 64, 256, 0, stream>>>(
        x16v, x16s, head, table, Wp, out);
}